// Round 1
// baseline (382.339 us; speedup 1.0000x reference)
//
#include <hip/hip_runtime.h>
#include <stdint.h>

#define HDIM 1024
#define NHEAD 16
#define HD 64
#define NB 4
#define SEQ 2048
#define NROWS (NB*SEQ)   // 8192
#define NBH (NB*NHEAD)   // 64

typedef __attribute__((ext_vector_type(8))) short short8;
typedef __attribute__((ext_vector_type(4))) float f32x4;

typedef __attribute__((address_space(1))) const void gk_t;  // global (for global_load_lds src)
typedef __attribute__((address_space(3))) void lds_t;       // LDS (dest)

static __device__ __forceinline__ unsigned short f2bf(float f) {
  union { float f; unsigned u; } v; v.f = f;
  unsigned r = v.u + 0x7fffu + ((v.u >> 16) & 1u);   // RNE
  return (unsigned short)(r >> 16);
}

// ---------------------------------------------------------------- fp32->bf16
__global__ __launch_bounds__(256) void cvt_f32_bf16(const float* __restrict__ in,
                                                    unsigned short* __restrict__ out,
                                                    int n4) {
  int i = blockIdx.x * 256 + threadIdx.x;
  if (i >= n4) return;
  float4 v = reinterpret_cast<const float4*>(in)[i];
  ushort4 o;
  o.x = f2bf(v.x); o.y = f2bf(v.y); o.z = f2bf(v.z); o.w = f2bf(v.w);
  reinterpret_cast<ushort4*>(out)[i] = o;
}

// ------------------------------------------------- shared GEMM mainloop (bt)
// C[m][n] = sum_k A[m][k] * B[n][k];  A:[*][1024], B:[*][1024] bf16, K=1024.
// 128x128 tile, BK=64, 4 waves in 2x2, each wave 64x64 (4x4 frags of 16x16x32).
static __device__ __forceinline__ void gemm_mainloop(
    const unsigned short* __restrict__ A, const unsigned short* __restrict__ B,
    int rowA0, int rowB0,
    unsigned short* As, unsigned short* Bs,   // LDS [128][64] each, linear
    f32x4 acc[4][4]) {
  const int tid  = threadIdx.x;
  const int lane = tid & 63;
  const int wave = tid >> 6;
  const int wm = wave >> 1, wn = wave & 1;
  const int srow = lane >> 3;          // 0..7 row-within-chunk
  const int scol = (lane & 7) << 3;    // element col (0..56)

  for (int kt = 0; kt < 1024; kt += 64) {
    __syncthreads();                   // prev tile compute done
#pragma unroll
    for (int i = 0; i < 4; ++i) {
      int c = wave * 4 + i;            // chunk: rows 8c..8c+7
      const unsigned short* ga = A + (size_t)(rowA0 + c * 8 + srow) * 1024 + kt + scol;
      const unsigned short* gb = B + (size_t)(rowB0 + c * 8 + srow) * 1024 + kt + scol;
      __builtin_amdgcn_global_load_lds((gk_t*)ga, (lds_t*)(As + c * 512), 16, 0, 0);
      __builtin_amdgcn_global_load_lds((gk_t*)gb, (lds_t*)(Bs + c * 512), 16, 0, 0);
    }
    __syncthreads();                   // staging visible
#pragma unroll
    for (int kk = 0; kk < 2; ++kk) {
      short8 af[4], bfr[4];
#pragma unroll
      for (int mi = 0; mi < 4; ++mi)
        af[mi] = *reinterpret_cast<const short8*>(
            As + (wm * 64 + mi * 16 + (lane & 15)) * 64 + kk * 32 + ((lane >> 4) << 3));
#pragma unroll
      for (int ni = 0; ni < 4; ++ni)
        bfr[ni] = *reinterpret_cast<const short8*>(
            Bs + (wn * 64 + ni * 16 + (lane & 15)) * 64 + kk * 32 + ((lane >> 4) << 3));
#pragma unroll
      for (int mi = 0; mi < 4; ++mi)
#pragma unroll
        for (int ni = 0; ni < 4; ++ni)
          acc[mi][ni] = __builtin_amdgcn_mfma_f32_16x16x32_bf16(af[mi], bfr[ni], acc[mi][ni], 0, 0, 0);
    }
  }
}

// ------------------------------------------------------------- QKV GEMM
// Writes Q,K as [bh][s][d] bf16 and V transposed as [bh][d][s] bf16.
__global__ __launch_bounds__(256) void gemm_qkv(
    const unsigned short* __restrict__ xb, const unsigned short* __restrict__ wqkv,
    const float* __restrict__ bq, const float* __restrict__ bk, const float* __restrict__ bv,
    unsigned short* __restrict__ qout, unsigned short* __restrict__ kout,
    unsigned short* __restrict__ vtout) {
  __shared__ __align__(16) unsigned short As[128 * 64];
  __shared__ __align__(16) unsigned short Bs[128 * 64];
  f32x4 acc[4][4];
  const f32x4 zero = {0.f, 0.f, 0.f, 0.f};
#pragma unroll
  for (int i = 0; i < 4; ++i)
#pragma unroll
    for (int j = 0; j < 4; ++j) acc[i][j] = zero;

  const int bm0 = blockIdx.y * 128;
  const int bn0 = blockIdx.x * 128;
  gemm_mainloop(xb, wqkv, bm0, bn0, As, Bs, acc);

  const int lane = threadIdx.x & 63, wave = threadIdx.x >> 6;
  const int wm = wave >> 1, wn = wave & 1;
#pragma unroll
  for (int mi = 0; mi < 4; ++mi) {
    int m0 = bm0 + wm * 64 + mi * 16 + ((lane >> 4) << 2);
#pragma unroll
    for (int ni = 0; ni < 4; ++ni) {
      int n = bn0 + wn * 64 + ni * 16 + (lane & 15);
      int which = n >> 10;
      int nc = n & 1023;
      float bias = (which == 0 ? bq : which == 1 ? bk : bv)[nc];
      int h = nc >> 6, d = nc & 63;
#pragma unroll
      for (int r = 0; r < 4; ++r) {
        int m = m0 + r;
        int b = m >> 11, s = m & 2047;
        unsigned short val = f2bf(acc[mi][ni][r] + bias);
        int bh = b * NHEAD + h;
        if (which == 2) {
          vtout[(((size_t)bh * HD + d) << 11) + s] = val;
        } else {
          unsigned short* dst = (which == 0) ? qout : kout;
          dst[(((size_t)bh << 11) + s) * HD + d] = val;
        }
      }
    }
  }
}

// ------------------------------------------------------------- out-proj GEMM
__global__ __launch_bounds__(256) void gemm_proj(
    const unsigned short* __restrict__ ab, const unsigned short* __restrict__ wob,
    const float* __restrict__ bo, const float* __restrict__ x, float* __restrict__ y) {
  __shared__ __align__(16) unsigned short As[128 * 64];
  __shared__ __align__(16) unsigned short Bs[128 * 64];
  f32x4 acc[4][4];
  const f32x4 zero = {0.f, 0.f, 0.f, 0.f};
#pragma unroll
  for (int i = 0; i < 4; ++i)
#pragma unroll
    for (int j = 0; j < 4; ++j) acc[i][j] = zero;

  const int bm0 = blockIdx.y * 128;
  const int bn0 = blockIdx.x * 128;
  gemm_mainloop(ab, wob, bm0, bn0, As, Bs, acc);

  const int lane = threadIdx.x & 63, wave = threadIdx.x >> 6;
  const int wm = wave >> 1, wn = wave & 1;
#pragma unroll
  for (int mi = 0; mi < 4; ++mi) {
    int m0 = bm0 + wm * 64 + mi * 16 + ((lane >> 4) << 2);
#pragma unroll
    for (int ni = 0; ni < 4; ++ni) {
      int n = bn0 + wn * 64 + ni * 16 + (lane & 15);
      float bias = bo[n];
#pragma unroll
      for (int r = 0; r < 4; ++r) {
        size_t idx = (size_t)(m0 + r) * HDIM + n;
        y[idx] = acc[mi][ni][r] + bias + x[idx];
      }
    }
  }
}

// ------------------------------------------------------------- flash attention
// grid (32 qtiles, 64 bh), 256 thr. Q-block 64 rows; wave owns 16 rows.
__global__ __launch_bounds__(256) void flash_attn(
    const unsigned short* __restrict__ Q, const unsigned short* __restrict__ K,
    const unsigned short* __restrict__ VT, const int* __restrict__ mask,
    unsigned short* __restrict__ O) {
  __shared__ __align__(16) char Ks[64 * 128];        // K tile [j][d], swizzled
  __shared__ __align__(16) char Vs[64 * 128];        // V^T tile [d][j], swizzled
  __shared__ __align__(16) char Ps[4 * 16 * 128];    // per-wave P [q][j], swizzled

  const int tid = threadIdx.x;
  const int lane = tid & 63, wave = tid >> 6;
  const int bh = blockIdx.y;
  const int b = bh >> 4, h = bh & 15;
  const int q0 = blockIdx.x * 64;

  // Q fragments (registers for whole kernel)
  const unsigned short* qptr =
      Q + ((size_t)bh * SEQ + q0 + wave * 16 + (lane & 15)) * HD + ((lane >> 4) << 3);
  short8 qf0 = *reinterpret_cast<const short8*>(qptr);
  short8 qf1 = *reinterpret_cast<const short8*>(qptr + 32);

  const f32x4 zero = {0.f, 0.f, 0.f, 0.f};
  f32x4 oacc[4];
#pragma unroll
  for (int i = 0; i < 4; ++i) oacc[i] = zero;
  float mrun[4], lrun[4];
#pragma unroll
  for (int r = 0; r < 4; ++r) { mrun[r] = -1e30f; lrun[r] = 0.f; }

  const int* mrow = mask + b * SEQ;
  const int srow = tid >> 2;           // 0..63
  const int scol = (tid & 3) << 4;     // 0,16,32,48 (elements)
  const int swzs = (srow & 7) << 4;
  const unsigned short* kbase = K + ((size_t)bh * SEQ + srow) * HD + scol;
  const unsigned short* vbase = VT + (((size_t)bh * HD + srow) << 11) + scol;
  const int cfrag = ((lane >> 4) << 3) * 2;   // byte col of this lane's frag

  for (int j0 = 0; j0 < SEQ; j0 += 64) {
    __syncthreads();
    { // stage K tile + V^T tile (swizzled ds_write_b128)
      const short8* ksrc = reinterpret_cast<const short8*>(kbase + (size_t)j0 * HD);
      short8 k0 = ksrc[0], k1 = ksrc[1];
      const short8* vsrc = reinterpret_cast<const short8*>(vbase + j0);
      short8 v0 = vsrc[0], v1 = vsrc[1];
      char* kd = Ks + srow * 128;
      *reinterpret_cast<short8*>(kd + ((scol * 2) ^ swzs))      = k0;
      *reinterpret_cast<short8*>(kd + ((scol * 2 + 16) ^ swzs)) = k1;
      char* vd = Vs + srow * 128;
      *reinterpret_cast<short8*>(vd + ((scol * 2) ^ swzs))      = v0;
      *reinterpret_cast<short8*>(vd + ((scol * 2 + 16) ^ swzs)) = v1;
    }
    __syncthreads();

    // ---- QK^T
    f32x4 sf[4];
#pragma unroll
    for (int ni = 0; ni < 4; ++ni) {
      sf[ni] = zero;
      int krow = ni * 16 + (lane & 15);
      const char* kr = Ks + krow * 128;
      int swz = (krow & 7) << 4;
      short8 b0 = *reinterpret_cast<const short8*>(kr + (cfrag ^ swz));
      short8 b1 = *reinterpret_cast<const short8*>(kr + ((cfrag + 64) ^ swz));
      sf[ni] = __builtin_amdgcn_mfma_f32_16x16x32_bf16(qf0, b0, sf[ni], 0, 0, 0);
      sf[ni] = __builtin_amdgcn_mfma_f32_16x16x32_bf16(qf1, b1, sf[ni], 0, 0, 0);
    }
    // ---- scale + mask
    float p[4][4];
#pragma unroll
    for (int ni = 0; ni < 4; ++ni) {
      bool msk = (mrow[j0 + ni * 16 + (lane & 15)] == 0);
#pragma unroll
      for (int r = 0; r < 4; ++r) {
        float s = sf[ni][r] * 0.125f;
        p[ni][r] = msk ? -1e9f : s;
      }
    }
    // ---- online softmax (per q-row r; stats shared across 16-lane group)
#pragma unroll
    for (int r = 0; r < 4; ++r) {
      float mx = fmaxf(fmaxf(p[0][r], p[1][r]), fmaxf(p[2][r], p[3][r]));
      mx = fmaxf(mx, __shfl_xor(mx, 1));
      mx = fmaxf(mx, __shfl_xor(mx, 2));
      mx = fmaxf(mx, __shfl_xor(mx, 4));
      mx = fmaxf(mx, __shfl_xor(mx, 8));
      float mnew = fmaxf(mrun[r], mx);
      float corr = __expf(mrun[r] - mnew);
      float rs = 0.f;
#pragma unroll
      for (int ni = 0; ni < 4; ++ni) { p[ni][r] = __expf(p[ni][r] - mnew); rs += p[ni][r]; }
      rs += __shfl_xor(rs, 1);
      rs += __shfl_xor(rs, 2);
      rs += __shfl_xor(rs, 4);
      rs += __shfl_xor(rs, 8);
      lrun[r] = lrun[r] * corr + rs;
      mrun[r] = mnew;
#pragma unroll
      for (int ni = 0; ni < 4; ++ni) oacc[ni][r] *= corr;
    }
    // ---- P -> per-wave LDS (bf16, swizzled)
    {
      char* pw = Ps + wave * 2048;
      int qb_ = (lane >> 4) << 2;
#pragma unroll
      for (int r = 0; r < 4; ++r) {
        int qr = qb_ + r;
        char* prow = pw + qr * 128;
        int swz = (qr & 7) << 4;
#pragma unroll
        for (int ni = 0; ni < 4; ++ni) {
          int kv = ni * 16 + (lane & 15);
          *reinterpret_cast<unsigned short*>(prow + ((kv * 2) ^ swz)) = f2bf(p[ni][r]);
        }
      }
    }
    asm volatile("s_waitcnt lgkmcnt(0)" ::: "memory");  // write->read same-wave order
    // ---- PV
    {
      const char* pr = Ps + wave * 2048 + (lane & 15) * 128;
      int swzp = ((lane & 15) & 7) << 4;
      short8 pa0 = *reinterpret_cast<const short8*>(pr + (cfrag ^ swzp));
      short8 pa1 = *reinterpret_cast<const short8*>(pr + ((cfrag + 64) ^ swzp));
#pragma unroll
      for (int ni = 0; ni < 4; ++ni) {
        int vrow = ni * 16 + (lane & 15);
        const char* vr = Vs + vrow * 128;
        int swz = (vrow & 7) << 4;
        short8 b0 = *reinterpret_cast<const short8*>(vr + (cfrag ^ swz));
        short8 b1 = *reinterpret_cast<const short8*>(vr + ((cfrag + 64) ^ swz));
        oacc[ni] = __builtin_amdgcn_mfma_f32_16x16x32_bf16(pa0, b0, oacc[ni], 0, 0, 0);
        oacc[ni] = __builtin_amdgcn_mfma_f32_16x16x32_bf16(pa1, b1, oacc[ni], 0, 0, 0);
      }
    }
  }

  // epilogue: normalize + write [b,s,h*64+d]
#pragma unroll
  for (int ni = 0; ni < 4; ++ni) {
#pragma unroll
    for (int r = 0; r < 4; ++r) {
      int s = q0 + wave * 16 + ((lane >> 4) << 2) + r;
      int d = ni * 16 + (lane & 15);
      float val = oacc[ni][r] / lrun[r];
      O[((size_t)b * SEQ + s) * HDIM + h * HD + d] = f2bf(val);
    }
  }
}

// ------------------------------------------------------------- LayerNorm (in-place)
__global__ __launch_bounds__(256) void layernorm(float* __restrict__ y,
                                                 const float* __restrict__ gamma,
                                                 const float* __restrict__ beta) {
  const int row = blockIdx.x;
  float* yr = y + (size_t)row * HDIM;
  const int tid = threadIdx.x;
  float4 v = reinterpret_cast<const float4*>(yr)[tid];
  float s = v.x + v.y + v.z + v.w;
  float s2 = v.x * v.x + v.y * v.y + v.z * v.z + v.w * v.w;
#pragma unroll
  for (int off = 1; off < 64; off <<= 1) {
    s += __shfl_xor(s, off);
    s2 += __shfl_xor(s2, off);
  }
  __shared__ float red[8];
  const int wave = tid >> 6, lane = tid & 63;
  if (lane == 0) { red[wave] = s; red[wave + 4] = s2; }
  __syncthreads();
  s = red[0] + red[1] + red[2] + red[3];
  s2 = red[4] + red[5] + red[6] + red[7];
  float mean = s * (1.f / HDIM);
  float var = s2 * (1.f / HDIM) - mean * mean;
  float rstd = rsqrtf(var + 1e-5f);
  float4 g = reinterpret_cast<const float4*>(gamma)[tid];
  float4 bt = reinterpret_cast<const float4*>(beta)[tid];
  float4 o;
  o.x = (v.x - mean) * rstd * g.x + bt.x;
  o.y = (v.y - mean) * rstd * g.y + bt.y;
  o.z = (v.z - mean) * rstd * g.z + bt.z;
  o.w = (v.w - mean) * rstd * g.w + bt.w;
  reinterpret_cast<float4*>(yr)[tid] = o;
}

// ----------------------------------------------------------------- launcher
extern "C" void kernel_launch(void* const* d_in, const int* in_sizes, int n_in,
                              void* d_out, int out_size, void* d_ws, size_t ws_size,
                              hipStream_t stream) {
  (void)in_sizes; (void)n_in; (void)out_size; (void)ws_size;
  const float* x     = (const float*)d_in[0];
  const int*   mask  = (const int*)d_in[1];
  const float* Wq    = (const float*)d_in[2];
  const float* bq    = (const float*)d_in[3];
  const float* Wk    = (const float*)d_in[4];
  const float* bk    = (const float*)d_in[5];
  const float* Wv    = (const float*)d_in[6];
  const float* bv    = (const float*)d_in[7];
  const float* Wo    = (const float*)d_in[8];
  const float* bo    = (const float*)d_in[9];
  const float* gamma = (const float*)d_in[10];
  const float* beta  = (const float*)d_in[11];
  float* out = (float*)d_out;

  char* ws = (char*)d_ws;
  // layout (bytes): xb 16.78M | wqkv 6.29M | wo 2.10M | q 16.78M | k 16.78M | vt 16.78M
  unsigned short* xb   = (unsigned short*)(ws);
  unsigned short* wqkv = (unsigned short*)(ws + 16777216);
  unsigned short* wo   = (unsigned short*)(ws + 16777216 + 6291456);
  unsigned short* q    = (unsigned short*)(ws + 25165824);
  unsigned short* k    = (unsigned short*)(ws + 25165824 + 16777216);
  unsigned short* vt   = (unsigned short*)(ws + 25165824 + 2 * 16777216);
  unsigned short* attn = xb;  // xb dead after gemm_qkv; reuse as attention output

  cvt_f32_bf16<<<8192, 256, 0, stream>>>(x, xb, NROWS * HDIM / 4);
  cvt_f32_bf16<<<1024, 256, 0, stream>>>(Wq, wqkv, 262144);
  cvt_f32_bf16<<<1024, 256, 0, stream>>>(Wk, wqkv + 1048576, 262144);
  cvt_f32_bf16<<<1024, 256, 0, stream>>>(Wv, wqkv + 2097152, 262144);
  cvt_f32_bf16<<<1024, 256, 0, stream>>>(Wo, wo, 262144);

  gemm_qkv<<<dim3(24, 64), 256, 0, stream>>>(xb, wqkv, bq, bk, bv, q, k, vt);
  flash_attn<<<dim3(32, 64), 256, 0, stream>>>(q, k, vt, mask, attn);
  gemm_proj<<<dim3(8, 64), 256, 0, stream>>>(attn, wo, bo, x, out);
  layernorm<<<NROWS, 256, 0, stream>>>(out, gamma, beta);
}

// Round 3
// 313.676 us; speedup vs baseline: 1.2189x; 1.2189x over previous
//
#include <hip/hip_runtime.h>
#include <stdint.h>

#define HDIM 1024
#define NHEAD 16
#define HD 64
#define NB 4
#define SEQ 2048
#define NROWS (NB*SEQ)   // 8192
#define NBH (NB*NHEAD)   // 64

typedef __attribute__((ext_vector_type(8))) short short8;
typedef __attribute__((ext_vector_type(4))) float f32x4;

typedef __attribute__((address_space(1))) const void gk_t;  // global (for global_load_lds src)
typedef __attribute__((address_space(3))) void lds_t;       // LDS (dest)

static __device__ __forceinline__ unsigned short f2bf(float f) {
  union { float f; unsigned u; } v; v.f = f;
  unsigned r = v.u + 0x7fffu + ((v.u >> 16) & 1u);   // RNE
  return (unsigned short)(r >> 16);
}

// ---------------------------------------------------------------- fp32->bf16
__global__ __launch_bounds__(256) void cvt_f32_bf16(const float* __restrict__ in,
                                                    unsigned short* __restrict__ out,
                                                    int n4) {
  int i = blockIdx.x * 256 + threadIdx.x;
  if (i >= n4) return;
  float4 v = reinterpret_cast<const float4*>(in)[i];
  ushort4 o;
  o.x = f2bf(v.x); o.y = f2bf(v.y); o.z = f2bf(v.z); o.w = f2bf(v.w);
  reinterpret_cast<ushort4*>(out)[i] = o;
}

// ---------------------------------------------------------------- mask->bias
__global__ __launch_bounds__(256) void mask_to_bias(const int* __restrict__ mask,
                                                    float* __restrict__ fb, int n) {
  int i = blockIdx.x * 256 + threadIdx.x;
  if (i < n) fb[i] = (mask[i] == 0) ? -1e9f : 0.0f;
}

// ------------------------------------------------- shared GEMM mainloop (bt)
// C[m][n] = sum_k A[m][k] * B[n][k];  A:[*][1024], B:[*][1024] bf16, K=1024.
// 128x128 tile, BK=64, 4 waves in 2x2, each wave 64x64 (4x4 frags of 16x16x32).
static __device__ __forceinline__ void gemm_mainloop(
    const unsigned short* __restrict__ A, const unsigned short* __restrict__ B,
    int rowA0, int rowB0,
    unsigned short* As, unsigned short* Bs,   // LDS [128][64] each, linear
    f32x4 acc[4][4]) {
  const int tid  = threadIdx.x;
  const int lane = tid & 63;
  const int wave = tid >> 6;
  const int wm = wave >> 1, wn = wave & 1;
  const int srow = lane >> 3;          // 0..7 row-within-chunk
  const int scol = (lane & 7) << 3;    // element col (0..56)

  for (int kt = 0; kt < 1024; kt += 64) {
    __syncthreads();                   // prev tile compute done
#pragma unroll
    for (int i = 0; i < 4; ++i) {
      int c = wave * 4 + i;            // chunk: rows 8c..8c+7
      const unsigned short* ga = A + (size_t)(rowA0 + c * 8 + srow) * 1024 + kt + scol;
      const unsigned short* gb = B + (size_t)(rowB0 + c * 8 + srow) * 1024 + kt + scol;
      __builtin_amdgcn_global_load_lds((gk_t*)ga, (lds_t*)(As + c * 512), 16, 0, 0);
      __builtin_amdgcn_global_load_lds((gk_t*)gb, (lds_t*)(Bs + c * 512), 16, 0, 0);
    }
    __syncthreads();                   // staging visible
#pragma unroll
    for (int kk = 0; kk < 2; ++kk) {
      short8 af[4], bfr[4];
#pragma unroll
      for (int mi = 0; mi < 4; ++mi)
        af[mi] = *reinterpret_cast<const short8*>(
            As + (wm * 64 + mi * 16 + (lane & 15)) * 64 + kk * 32 + ((lane >> 4) << 3));
#pragma unroll
      for (int ni = 0; ni < 4; ++ni)
        bfr[ni] = *reinterpret_cast<const short8*>(
            Bs + (wn * 64 + ni * 16 + (lane & 15)) * 64 + kk * 32 + ((lane >> 4) << 3));
#pragma unroll
      for (int mi = 0; mi < 4; ++mi)
#pragma unroll
        for (int ni = 0; ni < 4; ++ni)
          acc[mi][ni] = __builtin_amdgcn_mfma_f32_16x16x32_bf16(af[mi], bfr[ni], acc[mi][ni], 0, 0, 0);
    }
  }
}

// ------------------------------------------------------------- QKV GEMM
// Writes Q,K as [bh][s][d] bf16 and V transposed as [bh][d][s] bf16.
__global__ __launch_bounds__(256) void gemm_qkv(
    const unsigned short* __restrict__ xb, const unsigned short* __restrict__ wqkv,
    const float* __restrict__ bq, const float* __restrict__ bk, const float* __restrict__ bv,
    unsigned short* __restrict__ qout, unsigned short* __restrict__ kout,
    unsigned short* __restrict__ vtout) {
  __shared__ __align__(16) unsigned short As[128 * 64];
  __shared__ __align__(16) unsigned short Bs[128 * 64];
  f32x4 acc[4][4];
  const f32x4 zero = {0.f, 0.f, 0.f, 0.f};
#pragma unroll
  for (int i = 0; i < 4; ++i)
#pragma unroll
    for (int j = 0; j < 4; ++j) acc[i][j] = zero;

  const int bm0 = blockIdx.y * 128;
  const int bn0 = blockIdx.x * 128;
  gemm_mainloop(xb, wqkv, bm0, bn0, As, Bs, acc);

  const int lane = threadIdx.x & 63, wave = threadIdx.x >> 6;
  const int wm = wave >> 1, wn = wave & 1;
#pragma unroll
  for (int mi = 0; mi < 4; ++mi) {
    int m0 = bm0 + wm * 64 + mi * 16 + ((lane >> 4) << 2);
#pragma unroll
    for (int ni = 0; ni < 4; ++ni) {
      int n = bn0 + wn * 64 + ni * 16 + (lane & 15);
      int which = n >> 10;
      int nc = n & 1023;
      float bias = (which == 0 ? bq : which == 1 ? bk : bv)[nc];
      int h = nc >> 6, d = nc & 63;
#pragma unroll
      for (int r = 0; r < 4; ++r) {
        int m = m0 + r;
        int b = m >> 11, s = m & 2047;
        unsigned short val = f2bf(acc[mi][ni][r] + bias);
        int bh = b * NHEAD + h;
        if (which == 2) {
          vtout[(((size_t)bh * HD + d) << 11) + s] = val;
        } else {
          unsigned short* dst = (which == 0) ? qout : kout;
          dst[(((size_t)bh << 11) + s) * HD + d] = val;
        }
      }
    }
  }
}

// ------------------------------------------------------------- out-proj GEMM
__global__ __launch_bounds__(256) void gemm_proj(
    const unsigned short* __restrict__ ab, const unsigned short* __restrict__ wob,
    const float* __restrict__ bo, const float* __restrict__ x, float* __restrict__ y) {
  __shared__ __align__(16) unsigned short As[128 * 64];
  __shared__ __align__(16) unsigned short Bs[128 * 64];
  f32x4 acc[4][4];
  const f32x4 zero = {0.f, 0.f, 0.f, 0.f};
#pragma unroll
  for (int i = 0; i < 4; ++i)
#pragma unroll
    for (int j = 0; j < 4; ++j) acc[i][j] = zero;

  const int bm0 = blockIdx.y * 128;
  const int bn0 = blockIdx.x * 128;
  gemm_mainloop(ab, wob, bm0, bn0, As, Bs, acc);

  const int lane = threadIdx.x & 63, wave = threadIdx.x >> 6;
  const int wm = wave >> 1, wn = wave & 1;
#pragma unroll
  for (int mi = 0; mi < 4; ++mi) {
    int m0 = bm0 + wm * 64 + mi * 16 + ((lane >> 4) << 2);
#pragma unroll
    for (int ni = 0; ni < 4; ++ni) {
      int n = bn0 + wn * 64 + ni * 16 + (lane & 15);
      float bias = bo[n];
#pragma unroll
      for (int r = 0; r < 4; ++r) {
        size_t idx = (size_t)(m0 + r) * HDIM + n;
        y[idx] = acc[mi][ni][r] + bias + x[idx];
      }
    }
  }
}

// ------------------------------------------------------------- flash attention
// Swapped QK^T: sf = mfma(K_frag, Q_frag) -> S^T fragments with q = lane&15.
// Straight (unpermuted) K/V staging; in-register online softmax (2 shuffles);
// P routed to PV B-operand via small per-wave LDS buffer. Round-1 numerics.
__global__ __launch_bounds__(256) void flash_attn(
    const unsigned short* __restrict__ Q, const unsigned short* __restrict__ K,
    const unsigned short* __restrict__ VT, const float* __restrict__ fbias,
    unsigned short* __restrict__ O) {
  __shared__ __align__(16) char Ks[64 * 128];      // K tile [kv][d], XOR-swizzled
  __shared__ __align__(16) char Vs[64 * 128];      // V^T tile [d][kv], XOR-swizzled
  __shared__ __align__(16) char Ps[4 * 16 * 128];  // per-wave P [q16][kv64], XOR-swizzled

  const int tid = threadIdx.x;
  const int lane = tid & 63, wave = tid >> 6;
  const int l15 = lane & 15, g = lane >> 4;
  const int bh = blockIdx.y;
  const int b = bh >> 4, h = bh & 15;
  const int q0 = blockIdx.x * 64;

  // Q fragment: B-operand of swapped QK^T; q = l15, d = 8g+j (and +32)
  const unsigned short* qptr = Q + ((size_t)bh * SEQ + q0 + wave * 16 + l15) * HD + g * 8;
  short8 qf0 = *reinterpret_cast<const short8*>(qptr);
  short8 qf1 = *reinterpret_cast<const short8*>(qptr + 32);

  const f32x4 zero = {0.f, 0.f, 0.f, 0.f};
  f32x4 oacc[4];
#pragma unroll
  for (int i = 0; i < 4; ++i) oacc[i] = zero;
  float mrun = -1e30f, lrun = 0.f;

  // staging geometry: 256 threads cover 64 rows x 64 cols (2x short8 per lane)
  const int srow = tid >> 2;
  const int scol = (tid & 3) << 4;
  const int swzs = (srow & 7) << 4;
  char* kd0 = Ks + srow * 128 + ((scol * 2) ^ swzs);
  char* kd1 = Ks + srow * 128 + ((scol * 2 + 16) ^ swzs);
  char* vd0 = Vs + srow * 128 + ((scol * 2) ^ swzs);
  char* vd1 = Vs + srow * 128 + ((scol * 2 + 16) ^ swzs);
  const unsigned short* kg = K + ((size_t)bh * SEQ + srow) * HD + scol;
  const unsigned short* vg = VT + (((size_t)bh * HD + srow) << 11) + scol;

  // prefetch tile 0
  short8 kp0 = *reinterpret_cast<const short8*>(kg);
  short8 kp1 = *reinterpret_cast<const short8*>(kg + 8);
  short8 vp0 = *reinterpret_cast<const short8*>(vg);
  short8 vp1 = *reinterpret_cast<const short8*>(vg + 8);

  const int cfrag = g << 4;             // byte offset of this lane's k-group
  const int swzr = (l15 & 7) << 4;
  const float* fbrow = fbias + b * SEQ;
  char* prow = Ps + wave * 2048 + l15 * 128;   // this lane's P row (q = l15)

  for (int jt = 0; jt < SEQ / 64; ++jt) {
    const int j0 = jt * 64;
    __syncthreads();                    // prev tile compute done
    *reinterpret_cast<short8*>(kd0) = kp0;
    *reinterpret_cast<short8*>(kd1) = kp1;
    *reinterpret_cast<short8*>(vd0) = vp0;
    *reinterpret_cast<short8*>(vd1) = vp1;
    __syncthreads();                    // staging visible
    if (jt + 1 < SEQ / 64) {            // issue next-tile loads, hide under compute
      kp0 = *reinterpret_cast<const short8*>(kg + (size_t)(j0 + 64) * HD);
      kp1 = *reinterpret_cast<const short8*>(kg + (size_t)(j0 + 64) * HD + 8);
      vp0 = *reinterpret_cast<const short8*>(vg + j0 + 64);
      vp1 = *reinterpret_cast<const short8*>(vg + j0 + 64 + 8);
    }

    // ---- QK^T swapped: lane holds S^T for kv = 16ni + 4g + r, q = l15
    f32x4 sf[4];
#pragma unroll
    for (int ni = 0; ni < 4; ++ni) {
      const char* kr = Ks + (ni * 16 + l15) * 128;
      short8 a0 = *reinterpret_cast<const short8*>(kr + (cfrag ^ swzr));
      short8 a1 = *reinterpret_cast<const short8*>(kr + ((cfrag + 64) ^ swzr));
      f32x4 t = __builtin_amdgcn_mfma_f32_16x16x32_bf16(a0, qf0, zero, 0, 0, 0);
      sf[ni] = __builtin_amdgcn_mfma_f32_16x16x32_bf16(a1, qf1, t, 0, 0, 0);
    }

    // ---- scale + additive mask bias; kv = 16ni + 4g + r
    float p[4][4];
#pragma unroll
    for (int ni = 0; ni < 4; ++ni) {
      f32x4 fbv = *reinterpret_cast<const f32x4*>(fbrow + j0 + ni * 16 + 4 * g);
#pragma unroll
      for (int r = 0; r < 4; ++r) p[ni][r] = sf[ni][r] * 0.125f + fbv[r];
    }

    // ---- in-register online softmax (column q = l15; 2 shuffles per reduce)
    float mx = p[0][0];
#pragma unroll
    for (int ni = 0; ni < 4; ++ni)
#pragma unroll
      for (int r = 0; r < 4; ++r) mx = fmaxf(mx, p[ni][r]);
    mx = fmaxf(mx, __shfl_xor(mx, 16));
    mx = fmaxf(mx, __shfl_xor(mx, 32));

    float mnew = fmaxf(mrun, mx);
    float corr = __expf(mrun - mnew);
    lrun *= corr;
#pragma unroll
    for (int di = 0; di < 4; ++di) oacc[di] *= corr;
    mrun = mnew;

    float rs = 0.f;
#pragma unroll
    for (int ni = 0; ni < 4; ++ni)
#pragma unroll
      for (int r = 0; r < 4; ++r) {
        p[ni][r] = __expf(p[ni][r] - mnew);
        rs += p[ni][r];
      }
    rs += __shfl_xor(rs, 16);
    rs += __shfl_xor(rs, 32);
    lrun += rs;

    // ---- P -> per-wave LDS [q][kv] (packed pair writes), then read B-frags
#pragma unroll
    for (int ni = 0; ni < 4; ++ni) {
      unsigned lo_, hi_;
      asm("v_cvt_pk_bf16_f32 %0, %1, %2" : "=v"(lo_) : "v"(p[ni][0]), "v"(p[ni][1]));
      asm("v_cvt_pk_bf16_f32 %0, %1, %2" : "=v"(hi_) : "v"(p[ni][2]), "v"(p[ni][3]));
      *reinterpret_cast<uint2*>(prow + ((32 * ni + 8 * g) ^ swzr)) = make_uint2(lo_, hi_);
    }
    asm volatile("s_waitcnt lgkmcnt(0)" ::: "memory");
    __builtin_amdgcn_sched_barrier(0);
    short8 pb0 = *reinterpret_cast<const short8*>(prow + (cfrag ^ swzr));          // kv=8g+j
    short8 pb1 = *reinterpret_cast<const short8*>(prow + ((cfrag + 64) ^ swzr));   // kv=32+8g+j

    // ---- PV: oacc = V^T(frag A) x P^T(frag B) = O^T, cols q = l15
#pragma unroll
    for (int di = 0; di < 4; ++di) {
      const char* vr = Vs + (di * 16 + l15) * 128;
      short8 va0 = *reinterpret_cast<const short8*>(vr + (cfrag ^ swzr));
      short8 va1 = *reinterpret_cast<const short8*>(vr + ((cfrag + 64) ^ swzr));
      oacc[di] = __builtin_amdgcn_mfma_f32_16x16x32_bf16(va0, pb0, oacc[di], 0, 0, 0);
      oacc[di] = __builtin_amdgcn_mfma_f32_16x16x32_bf16(va1, pb1, oacc[di], 0, 0, 0);
    }
  }

  // ---- epilogue: normalize, transpose via LDS (reuse Ks), coalesced store
  __syncthreads();
  {
    float inv = 1.0f / lrun;
    char* orow_lds = Ks + (wave * 16 + l15) * 128;   // row = q within block
#pragma unroll
    for (int di = 0; di < 4; ++di) {
      float e0 = oacc[di][0] * inv, e1 = oacc[di][1] * inv;
      float e2 = oacc[di][2] * inv, e3 = oacc[di][3] * inv;
      unsigned lo_, hi_;
      asm("v_cvt_pk_bf16_f32 %0, %1, %2" : "=v"(lo_) : "v"(e0), "v"(e1));
      asm("v_cvt_pk_bf16_f32 %0, %1, %2" : "=v"(hi_) : "v"(e2), "v"(e3));
      char* dst = orow_lds + ((32 * di + 8 * g) ^ swzr);
      *reinterpret_cast<uint2*>(dst) = make_uint2(lo_, hi_);
    }
  }
  __syncthreads();
  {
    int q = tid >> 2;
    int c4 = tid & 3;
    int swz = (q & 7) << 4;
    const char* src = Ks + q * 128;
    short8 o0 = *reinterpret_cast<const short8*>(src + ((c4 * 32) ^ swz));
    short8 o1 = *reinterpret_cast<const short8*>(src + ((c4 * 32 + 16) ^ swz));
    unsigned short* orow = O + ((size_t)b * SEQ + q0 + q) * HDIM + h * 64 + c4 * 16;
    *reinterpret_cast<short8*>(orow) = o0;
    *reinterpret_cast<short8*>(orow + 8) = o1;
  }
}

// ------------------------------------------------------------- LayerNorm (in-place)
__global__ __launch_bounds__(256) void layernorm(float* __restrict__ y,
                                                 const float* __restrict__ gamma,
                                                 const float* __restrict__ beta) {
  const int row = blockIdx.x;
  float* yr = y + (size_t)row * HDIM;
  const int tid = threadIdx.x;
  float4 v = reinterpret_cast<const float4*>(yr)[tid];
  float s = v.x + v.y + v.z + v.w;
  float s2 = v.x * v.x + v.y * v.y + v.z * v.z + v.w * v.w;
#pragma unroll
  for (int off = 1; off < 64; off <<= 1) {
    s += __shfl_xor(s, off);
    s2 += __shfl_xor(s2, off);
  }
  __shared__ float red[8];
  const int wave = tid >> 6, lane = tid & 63;
  if (lane == 0) { red[wave] = s; red[wave + 4] = s2; }
  __syncthreads();
  s = red[0] + red[1] + red[2] + red[3];
  s2 = red[4] + red[5] + red[6] + red[7];
  float mean = s * (1.f / HDIM);
  float var = s2 * (1.f / HDIM) - mean * mean;
  float rstd = rsqrtf(var + 1e-5f);
  float4 g = reinterpret_cast<const float4*>(gamma)[tid];
  float4 bt = reinterpret_cast<const float4*>(beta)[tid];
  float4 o;
  o.x = (v.x - mean) * rstd * g.x + bt.x;
  o.y = (v.y - mean) * rstd * g.y + bt.y;
  o.z = (v.z - mean) * rstd * g.z + bt.z;
  o.w = (v.w - mean) * rstd * g.w + bt.w;
  reinterpret_cast<float4*>(yr)[tid] = o;
}

// ----------------------------------------------------------------- launcher
extern "C" void kernel_launch(void* const* d_in, const int* in_sizes, int n_in,
                              void* d_out, int out_size, void* d_ws, size_t ws_size,
                              hipStream_t stream) {
  (void)in_sizes; (void)n_in; (void)out_size; (void)ws_size;
  const float* x     = (const float*)d_in[0];
  const int*   mask  = (const int*)d_in[1];
  const float* Wq    = (const float*)d_in[2];
  const float* bq    = (const float*)d_in[3];
  const float* Wk    = (const float*)d_in[4];
  const float* bk    = (const float*)d_in[5];
  const float* Wv    = (const float*)d_in[6];
  const float* bv    = (const float*)d_in[7];
  const float* Wo    = (const float*)d_in[8];
  const float* bo    = (const float*)d_in[9];
  const float* gamma = (const float*)d_in[10];
  const float* beta  = (const float*)d_in[11];
  float* out = (float*)d_out;

  char* ws = (char*)d_ws;
  // layout (bytes): xb 16.78M | wqkv 6.29M | wo 2.10M | q 16.78M | k 16.78M | vt 16.78M
  unsigned short* xb   = (unsigned short*)(ws);
  unsigned short* wqkv = (unsigned short*)(ws + 16777216);
  unsigned short* wo   = (unsigned short*)(ws + 16777216 + 6291456);
  unsigned short* q    = (unsigned short*)(ws + 25165824);
  unsigned short* k    = (unsigned short*)(ws + 25165824 + 16777216);
  unsigned short* vt   = (unsigned short*)(ws + 25165824 + 2 * 16777216);
  unsigned short* attn = xb;                 // xb dead after gemm_qkv
  float* fbias = (float*)(ws + 16777216);    // wqkv region dead after gemm_qkv

  cvt_f32_bf16<<<8192, 256, 0, stream>>>(x, xb, NROWS * HDIM / 4);
  cvt_f32_bf16<<<1024, 256, 0, stream>>>(Wq, wqkv, 262144);
  cvt_f32_bf16<<<1024, 256, 0, stream>>>(Wk, wqkv + 1048576, 262144);
  cvt_f32_bf16<<<1024, 256, 0, stream>>>(Wv, wqkv + 2097152, 262144);
  cvt_f32_bf16<<<1024, 256, 0, stream>>>(Wo, wo, 262144);

  gemm_qkv<<<dim3(24, 64), 256, 0, stream>>>(xb, wqkv, bq, bk, bv, q, k, vt);
  mask_to_bias<<<32, 256, 0, stream>>>(mask, fbias, NB * SEQ);
  flash_attn<<<dim3(32, 64), 256, 0, stream>>>(q, k, vt, fbias, attn);
  gemm_proj<<<dim3(8, 64), 256, 0, stream>>>(attn, wo, bo, x, out);
  layernorm<<<NROWS, 256, 0, stream>>>(out, gamma, beta);
}